// Round 3
// baseline (581.363 us; speedup 1.0000x reference)
//
#include <hip/hip_runtime.h>
#include <cstdint>
#include <cstddef>

#define NN 50000
#define NE 1600000
#define ET (NE + NN)          // edges + self loops
#define NG 64
#define SCAN_BLOCKS ((NN + 255) / 256)   // 196

// ---------------- K0: transpose W1 [512][64] -> Wt2 k-packed float4: Wt2f4[k4*64 + c] = W1[4k4..4k4+4][c]
__global__ void k_wt(const float* __restrict__ W1, float* __restrict__ Wt2) {
    int id = blockIdx.x * 256 + threadIdx.x;
    if (id >= 128 * 64) return;
    int k4 = id >> 6, c = id & 63;
    float4 v;
    v.x = W1[(k4 * 4 + 0) * 64 + c];
    v.y = W1[(k4 * 4 + 1) * 64 + c];
    v.z = W1[(k4 * 4 + 2) * 64 + c];
    v.w = W1[(k4 * 4 + 3) * 64 + c];
    reinterpret_cast<float4*>(Wt2)[id] = v;
}

// ---------------- K1: h1 = x @ W1, fused alpha_src/alpha_dst reductions.
// Block = 256 thr: tr = t>>4 -> rows {n0+tr+16i}, tc = t&15 -> cols {4tc..4tc+3}
__global__ __launch_bounds__(256) void k_gemm1(
    const float* __restrict__ x, const float* __restrict__ Wt2,
    const float* __restrict__ aS, const float* __restrict__ aD,
    float* __restrict__ h1, float* __restrict__ as1, float* __restrict__ ad1) {
    int t = threadIdx.x;
    int tr = t >> 4, tc = t & 15;
    int n0 = blockIdx.x * 64;
    const float4* xf = reinterpret_cast<const float4*>(x);
    const float4* wf = reinterpret_cast<const float4*>(Wt2);

    float acc[4][4];
#pragma unroll
    for (int i = 0; i < 4; ++i)
#pragma unroll
        for (int j = 0; j < 4; ++j) acc[i][j] = 0.f;

    int rows[4];
#pragma unroll
    for (int i = 0; i < 4; ++i) {
        int r = n0 + tr + 16 * i;
        rows[i] = (r < NN) ? r : (NN - 1);   // clamp for loads; stores guarded below
    }

#pragma unroll 2
    for (int k4 = 0; k4 < 128; ++k4) {
        float4 wv[4];
#pragma unroll
        for (int j = 0; j < 4; ++j) wv[j] = wf[k4 * 64 + tc * 4 + j];
#pragma unroll
        for (int i = 0; i < 4; ++i) {
            float4 xv = xf[rows[i] * 128 + k4];
#pragma unroll
            for (int j = 0; j < 4; ++j)
                acc[i][j] += xv.x * wv[j].x + xv.y * wv[j].y + xv.z * wv[j].z + xv.w * wv[j].w;
        }
    }

    // epilogue: store h1 + attention dot-products
    int hh = tc >> 1;                 // head of this lane's 4 cols
    int cb = (tc & 1) * 4;            // channel base within head
#pragma unroll
    for (int i = 0; i < 4; ++i) {
        int r = n0 + tr + 16 * i;
        if (r >= NN) continue;
        float4 hv = make_float4(acc[i][0], acc[i][1], acc[i][2], acc[i][3]);
        reinterpret_cast<float4*>(h1)[r * 16 + tc] = hv;
        float ps = acc[i][0] * aS[hh * 8 + cb + 0] + acc[i][1] * aS[hh * 8 + cb + 1] +
                   acc[i][2] * aS[hh * 8 + cb + 2] + acc[i][3] * aS[hh * 8 + cb + 3];
        float pd = acc[i][0] * aD[hh * 8 + cb + 0] + acc[i][1] * aD[hh * 8 + cb + 1] +
                   acc[i][2] * aD[hh * 8 + cb + 2] + acc[i][3] * aD[hh * 8 + cb + 3];
        ps += __shfl_xor(ps, 1);
        pd += __shfl_xor(pd, 1);
        if ((tc & 1) == 0) { as1[r * 8 + hh] = ps; ad1[r * 8 + hh] = pd; }
    }
}

// ---------------- CSR build
__global__ void k_hist(const int* __restrict__ edst, int* __restrict__ deg) {
    int e = blockIdx.x * 256 + threadIdx.x;
    if (e >= ET) return;
    int d = (e < NE) ? edst[e] : (e - NE);
    atomicAdd(&deg[d], 1);
}

__global__ __launch_bounds__(256) void k_scan1(const int* __restrict__ deg,
                                               int* __restrict__ offs, int* __restrict__ bsum) {
    __shared__ int lds_w[4];
    int i = blockIdx.x * 256 + threadIdx.x;
    int v = (i < NN) ? deg[i] : 0;
    int lane = threadIdx.x & 63, wid = threadIdx.x >> 6;
    int incl = v;
#pragma unroll
    for (int ofs = 1; ofs < 64; ofs <<= 1) {
        int o = __shfl_up(incl, ofs);
        if (lane >= ofs) incl += o;
    }
    if (lane == 63) lds_w[wid] = incl;
    __syncthreads();
    int wadd = 0;
    for (int w = 0; w < wid; ++w) wadd += lds_w[w];
    incl += wadd;
    if (i < NN) offs[i] = incl - v;
    if (threadIdx.x == 255) bsum[blockIdx.x] = incl;
}

__global__ void k_scan2(const int* __restrict__ bsum, int* __restrict__ bpre) {
    __shared__ int lds_w[4];
    int lane = threadIdx.x & 63, wid = threadIdx.x >> 6;
    int v = (threadIdx.x < SCAN_BLOCKS) ? bsum[threadIdx.x] : 0;
    int incl = v;
#pragma unroll
    for (int ofs = 1; ofs < 64; ofs <<= 1) {
        int o = __shfl_up(incl, ofs);
        if (lane >= ofs) incl += o;
    }
    if (lane == 63) lds_w[wid] = incl;
    __syncthreads();
    int wadd = 0;
    for (int w = 0; w < wid; ++w) wadd += lds_w[w];
    incl += wadd;
    bpre[threadIdx.x] = incl - v;
}

__global__ void k_scan3(int* __restrict__ offs, const int* __restrict__ bpre, int* __restrict__ cursor) {
    int i = blockIdx.x * 256 + threadIdx.x;
    if (i < NN) {
        int o = offs[i] + bpre[blockIdx.x];
        offs[i] = o;
        cursor[i] = o;
    }
    if (i == 0) offs[NN] = ET;
}

__global__ void k_scatter(const int* __restrict__ esrc, const int* __restrict__ edst,
                          int* __restrict__ cursor, int* __restrict__ csr) {
    int e = blockIdx.x * 256 + threadIdx.x;
    if (e >= ET) return;
    int s, d;
    if (e < NE) { s = esrc[e]; d = edst[e]; } else { s = d = e - NE; }
    int pos = atomicAdd(&cursor[d], 1);
    csr[pos] = s;
}

// ---------------- K4: layer-1 attention aggregation. One wave per dst; lane = (head<<3)|ch.
__global__ __launch_bounds__(256) void k_agg1(
    const int* __restrict__ offs, const int* __restrict__ csr,
    const float* __restrict__ h1, const float* __restrict__ as1, const float* __restrict__ ad1,
    const float* __restrict__ bias1, float* __restrict__ h1o) {
    int l = threadIdx.x & 63;
    int dst = blockIdx.x * 4 + (threadIdx.x >> 6);
    if (dst >= NN) return;
    int h = l >> 3;
    int beg = offs[dst], end = offs[dst + 1];
    float adh = ad1[dst * 8 + h];
    float acc = 0.f, dsum = 0.f;
#pragma clang loop unroll_count(2)
    for (int j = beg; j < end; ++j) {
        int s = csr[j];
        float e = as1[s * 8 + h] + adh;
        e = (e > 0.f) ? e : 0.2f * e;
        float w = __expf(e);
        acc += w * h1[s * 64 + l];
        dsum += w;
    }
    float v = acc / (dsum + 1e-16f) + bias1[l];
    v = (v > 0.f) ? v : (__expf(v) - 1.f);   // ELU
    h1o[dst * 64 + l] = v;
}

// ---------------- K6: h2 = h1o @ W2 (+ alpha2 reductions). 32 lanes per node.
__global__ __launch_bounds__(256) void k_gemm2(
    const float* __restrict__ h1o, const float* __restrict__ W2,
    const float* __restrict__ aS, const float* __restrict__ aD,
    float* __restrict__ h2, float* __restrict__ as2, float* __restrict__ ad2) {
    int c = threadIdx.x & 31;
    int n = blockIdx.x * 8 + (threadIdx.x >> 5);
    if (n >= NN) return;
    const float4* hf = reinterpret_cast<const float4*>(h1o + n * 64);
    float acc = 0.f;
#pragma unroll
    for (int k4 = 0; k4 < 16; ++k4) {
        float4 hv = hf[k4];
        acc += hv.x * W2[(k4 * 4 + 0) * 32 + c] + hv.y * W2[(k4 * 4 + 1) * 32 + c] +
               hv.z * W2[(k4 * 4 + 2) * 32 + c] + hv.w * W2[(k4 * 4 + 3) * 32 + c];
    }
    h2[n * 32 + c] = acc;
    float ps = acc * aS[c], pd = acc * aD[c];
#pragma unroll
    for (int o = 1; o < 32; o <<= 1) { ps += __shfl_xor(ps, o); pd += __shfl_xor(pd, o); }
    if (c == 0) { as2[n] = ps; ad2[n] = pd; }
}

// ---------------- K7: layer-2 aggregation. Half-wave (32 lanes) per dst.
__global__ __launch_bounds__(256) void k_agg2(
    const int* __restrict__ offs, const int* __restrict__ csr,
    const float* __restrict__ h2, const float* __restrict__ as2, const float* __restrict__ ad2,
    const float* __restrict__ bias2, float* __restrict__ o2) {
    int c = threadIdx.x & 31;
    int dst = blockIdx.x * 8 + (threadIdx.x >> 5);
    if (dst >= NN) return;
    int beg = offs[dst], end = offs[dst + 1];
    float adh = ad2[dst];
    float acc = 0.f, dsum = 0.f;
#pragma clang loop unroll_count(2)
    for (int j = beg; j < end; ++j) {
        int s = csr[j];
        float e = as2[s] + adh;
        e = (e > 0.f) ? e : 0.2f * e;
        float w = __expf(e);
        acc += w * h2[s * 32 + c];
        dsum += w;
    }
    o2[dst * 32 + c] = acc / (dsum + 1e-16f) + bias2[c];
}

// ---------------- K8: graph boundaries from sorted batch. lo[g] = first node with batch >= g.
__global__ void k_bound(const int* __restrict__ batch, int* __restrict__ lo) {
    int n = blockIdx.x * 256 + threadIdx.x;
    if (n >= NN) return;
    int b = batch[n];
    if (n == 0) {
        for (int g = 0; g <= b; ++g) lo[g] = 0;
    } else {
        int pb = batch[n - 1];
        for (int g = pb + 1; g <= b; ++g) lo[g] = n;
    }
    if (n == NN - 1) {
        for (int g = b + 1; g <= NG; ++g) lo[g] = NN;
    }
}

// ---------------- K9: pooled sums. 4 blocks per graph, partial-reduce in LDS, one atomic per (block, ch).
__global__ __launch_bounds__(256) void k_pool(const float* __restrict__ o2, const int* __restrict__ lo,
                                              float* __restrict__ pooled) {
    __shared__ float red[256];
    int g = blockIdx.x & 63, q = blockIdx.x >> 6;
    int beg = lo[g], end = lo[g + 1];
    int c = threadIdx.x & 31, row = threadIdx.x >> 5;
    float s = 0.f;
    for (int n = beg + q * 8 + row; n < end; n += 32) s += o2[n * 32 + c];
    red[threadIdx.x] = s;
    __syncthreads();
    for (int rr = 4; rr >= 1; rr >>= 1) {
        if (row < rr) red[threadIdx.x] += red[(row + rr) * 32 + c];
        __syncthreads();
    }
    if (row == 0) atomicAdd(&pooled[g * 32 + c], red[c]);
}

// ---------------- K10: mean + final linear -> out[64][2]
__global__ void k_fin(const float* __restrict__ pooled, const int* __restrict__ lo,
                      const float* __restrict__ lw, const float* __restrict__ lb,
                      float* __restrict__ out) {
    int t = threadIdx.x;
    if (t >= 128) return;
    int g = t >> 1, o = t & 1;
    int cnt = lo[g + 1] - lo[g];
    float inv = 1.f / fmaxf((float)cnt, 1.f);
    float s = 0.f;
#pragma unroll
    for (int c = 0; c < 32; ++c) s += pooled[g * 32 + c] * lw[c * 2 + o];
    out[g * 2 + o] = s * inv + lb[o];
}

// ----------------------------------------------------------------------------
extern "C" void kernel_launch(void* const* d_in, const int* in_sizes, int n_in,
                              void* d_out, int out_size, void* d_ws, size_t ws_size,
                              hipStream_t stream) {
    const float* x   = (const float*)d_in[0];
    const int*   ei  = (const int*)d_in[1];     // [2][NE]
    const int*   bat = (const int*)d_in[2];
    const float* W1  = (const float*)d_in[3];
    const float* aS1 = (const float*)d_in[4];
    const float* aD1 = (const float*)d_in[5];
    const float* b1  = (const float*)d_in[6];
    const float* W2  = (const float*)d_in[7];
    const float* aS2 = (const float*)d_in[8];
    const float* aD2 = (const float*)d_in[9];
    const float* b2  = (const float*)d_in[10];
    const float* lw  = (const float*)d_in[11];
    const float* lb  = (const float*)d_in[12];
    float* out = (float*)d_out;

    const int* esrc = ei;
    const int* edst = ei + NE;

    char* ws = (char*)d_ws;
    size_t off = 0;
    auto alloc = [&](size_t bytes) -> void* {
        off = (off + 255) & ~(size_t)255;
        void* p = ws + off;
        off += bytes;
        return p;
    };

    float* regA = (float*)alloc((size_t)NN * 64 * 4);   // h1; later reused: h2 @ 0, o2 @ NN*32
    float* h1   = regA;
    float* h2   = regA;                                  // alias (h1 dead after k_agg1)
    float* o2   = regA + (size_t)NN * 32;                // alias
    float* h1o  = (float*)alloc((size_t)NN * 64 * 4);
    float* as1  = (float*)alloc((size_t)NN * 8 * 4);
    float* ad1  = (float*)alloc((size_t)NN * 8 * 4);
    float* as2  = (float*)alloc((size_t)NN * 4);
    float* ad2  = (float*)alloc((size_t)NN * 4);
    int*   offs = (int*)alloc((size_t)(NN + 1) * 4);
    int*   deg  = (int*)alloc((size_t)NN * 4);
    int*   cur  = (int*)alloc((size_t)NN * 4);
    int*   csr  = (int*)alloc((size_t)ET * 4);
    float* Wt2  = (float*)alloc((size_t)512 * 64 * 4);
    int*   bsum = (int*)alloc(256 * 4);
    int*   bpre = (int*)alloc(256 * 4);
    float* pooled = (float*)alloc((size_t)NG * 32 * 4);
    int*   lo   = (int*)alloc((size_t)(NG + 1) * 4);
    if (off > ws_size) return;   // workspace too small: leave d_out poisoned (visible failure)

    hipMemsetAsync(deg, 0, (size_t)NN * 4, stream);
    hipMemsetAsync(pooled, 0, (size_t)NG * 32 * 4, stream);

    k_wt<<<32, 256, 0, stream>>>(W1, Wt2);
    k_gemm1<<<(NN + 63) / 64, 256, 0, stream>>>(x, Wt2, aS1, aD1, h1, as1, ad1);

    int eblocks = (ET + 255) / 256;
    k_hist<<<eblocks, 256, 0, stream>>>(edst, deg);
    k_scan1<<<SCAN_BLOCKS, 256, 0, stream>>>(deg, offs, bsum);
    k_scan2<<<1, 256, 0, stream>>>(bsum, bpre);
    k_scan3<<<SCAN_BLOCKS, 256, 0, stream>>>(offs, bpre, cur);
    k_scatter<<<eblocks, 256, 0, stream>>>(esrc, edst, cur, csr);

    k_agg1<<<(NN + 3) / 4, 256, 0, stream>>>(offs, csr, h1, as1, ad1, b1, h1o);
    k_gemm2<<<(NN + 7) / 8, 256, 0, stream>>>(h1o, W2, aS2, aD2, h2, as2, ad2);
    k_agg2<<<(NN + 7) / 8, 256, 0, stream>>>(offs, csr, h2, as2, ad2, b2, o2);

    k_bound<<<SCAN_BLOCKS, 256, 0, stream>>>(bat, lo);
    k_pool<<<NG * 4, 256, 0, stream>>>(o2, lo, pooled);
    k_fin<<<1, 128, 0, stream>>>(pooled, lo, lw, lb, out);
}